// Round 2
// baseline (281.316 us; speedup 1.0000x reference)
//
#include <hip/hip_runtime.h>
#include <math.h>

namespace {

typedef float f4 __attribute__((ext_vector_type(4)));

constexpr int PPW  = 4;                    // points per wave (one per 16-lane group)
constexpr int WPB  = 4;                    // waves per block
constexpr int PPB  = PPW * WPB;            // 16 points per block
constexpr int NPTS = 256 * 128;            // 32768 points total
constexpr int GRID = NPTS / PPB;           // 2048 blocks
constexpr int OUTS = 257;                  // D+1
constexpr size_t HOFF = (size_t)NPTS * OUTS;
constexpr int LSTR = 256;                  // no pad: reads are 64-consec-dword (2-way, free)

__device__ __forceinline__ float frcp(float x)   { return __builtin_amdgcn_rcpf(x); }
__device__ __forceinline__ float fsqrt_(float x) { return __builtin_amdgcn_sqrtf(x); }
// acosh(a) = log(a + sqrt(a^2-1)); fma keeps a^2-1 accurate near a=1
__device__ __forceinline__ float facosh(float a) {
  return __logf(a + fsqrt_(fmaf(a, a, -1.f)));
}
__device__ __forceinline__ void fsinhcosh(float x, float& sh, float& ch) {
  float e = __expf(x), ei = frcp(e);
  sh = 0.5f * (e - ei);
  ch = 0.5f * (e + ei);
}
__device__ __forceinline__ float fsinh(float x) {
  float e = __expf(x);
  return 0.5f * (e - frcp(e));
}
__device__ __forceinline__ float dot4(f4 a, f4 b) {
  return a.x * b.x + a.y * b.y + a.z * b.z + a.w * b.w;
}
__device__ __forceinline__ f4 fma4s(float a, f4 b, f4 c) {
  f4 av = {a, a, a, a};
  return __builtin_elementwise_fma(av, b, c);
}

// one butterfly step: x += rotate-within-row16(x, N)  — pure VALU (v_add_f32 + DPP),
// no LDS pipe, ~4cy dependent latency vs ~40cy for ds_swizzle/bpermute.
template <int CTRL>
__device__ __forceinline__ float dpp_add(float x) {
  int t = __builtin_amdgcn_update_dpp(0, __builtin_bit_cast(int, x), CTRL, 0xf, 0xf, true);
  return x + __builtin_bit_cast(float, t);
}

// sum across each 16-lane row via DPP rotations; rotations by 8,4,2,1 within a
// row of 16 compose to give every lane the full 16-lane sum.
template <int NB>
__device__ __forceinline__ void grp_reduce(float* v) {
#pragma unroll
  for (int i = 0; i < NB; ++i) {
    float t = v[i];
    t = dpp_add<0x128>(t);   // row_ror:8
    t = dpp_add<0x124>(t);   // row_ror:4
    t = dpp_add<0x122>(t);   // row_ror:2
    t = dpp_add<0x121>(t);   // row_ror:1
    v[i] = t;
  }
}

__global__ __launch_bounds__(256) void splmw_kernel(
    const float* __restrict__ xt, const float* __restrict__ xc,
    const float* __restrict__ xf, const float* __restrict__ xr,
    const float* __restrict__ Wt, const float* __restrict__ bt,
    const float* __restrict__ Wc, const float* __restrict__ bc,
    const float* __restrict__ Wf, const float* __restrict__ bf,
    const float* __restrict__ Wr, const float* __restrict__ br,
    const float* __restrict__ esp, const float* __restrict__ lwp,
    float* __restrict__ out) {
  // W^T staged as wlds[s*LSTR + d]; writes row-wise (lanes vary d, contiguous ->
  // 2-way, free); reads cover 64 consecutive dwords per instr + 4-group
  // broadcast -> 2-way, free.
  __shared__ float wlds[32 * LSTR];

  const int tid  = threadIdx.x;
  const int lane = tid & 63;
  const int m    = lane & 15;              // lane within 16-lane group
  const int grp  = lane >> 4;              // group (= point) within wave
  const int wv   = tid >> 6;
  const int pt   = blockIdx.x * PPB + wv * PPW + grp;  // this lane's point

  // tanh(effective_scale) via native exp
  float es2 = __expf(2.f * esp[0]);
  const float ts = (es2 - 1.f) * frcp(es2 + 1.f);
  // softmax of lorentz_weights
  float l0 = lwp[0], l1 = lwp[1], l2 = lwp[2], l3 = lwp[3];
  float mx = fmaxf(fmaxf(l0, l1), fmaxf(l2, l3));
  float e0 = __expf(l0 - mx), e1 = __expf(l1 - mx);
  float e2 = __expf(l2 - mx), e3 = __expf(l3 - mx);
  float ei = frcp(e0 + e1 + e2 + e3);
  const float wgt[4] = {e0 * ei, e1 * ei, e2 * ei, e3 * ei};

  const float* xsarr[4] = {xt, xc, xf, xr};
  const float* Wsarr[4] = {Wt, Wc, Wf, Wr};
  const float* Bsarr[4] = {bt, bc, bf, br};

  // h[c][j]: this lane's point's spatial dims 4m+64j .. +3
  // x0s[c]: time component; r2s[c] = ||spatial||^2 (group-uniform)
  f4    h[4][4];
  float x0s[4];
  float r2s[4];

#pragma unroll
  for (int c = 0; c < 4; ++c) {
    // ---- stage W_c transposed into LDS (thread tid owns W row d = tid) ----
    const float* Wp = Wsarr[c];
    f4 wrow[8];
#pragma unroll
    for (int k = 0; k < 8; ++k) wrow[k] = *(const f4*)(Wp + tid * 32 + 4 * k);
    __syncthreads();                       // prev channel's reads done
#pragma unroll
    for (int k = 0; k < 8; ++k) {
      wlds[(4 * k + 0) * LSTR + tid] = wrow[k].x;
      wlds[(4 * k + 1) * LSTR + tid] = wrow[k].y;
      wlds[(4 * k + 2) * LSTR + tid] = wrow[k].z;
      wlds[(4 * k + 3) * LSTR + tid] = wrow[k].w;
    }
    __syncthreads();

    // ---- encode: acc[j] = b + sum_s x[s] * W^T[s][4m+64j..] ----
    f4 acc[4];
    const float* bp = Bsarr[c];
#pragma unroll
    for (int j = 0; j < 4; ++j) acc[j] = *(const f4*)(bp + 4 * m + 64 * j);
    const float* xp = xsarr[c] + (size_t)pt * 32;   // group-uniform address
#pragma unroll
    for (int s4 = 0; s4 < 8; ++s4) {
      f4 xq = *(const f4*)(xp + 4 * s4);
      float xa[4] = {xq.x, xq.y, xq.z, xq.w};
#pragma unroll
      for (int si = 0; si < 4; ++si) {
        const float* wr = &wlds[(4 * s4 + si) * LSTR + 4 * m];
#pragma unroll
        for (int j = 0; j < 4; ++j)
          acc[j] = fma4s(xa[si], *(const f4*)(wr + 64 * j), acc[j]);
      }
    }

    // ---- to_hyperbolic (scalars once per lane) ----
    float pa = 0.f;
#pragma unroll
    for (int j = 0; j < 4; ++j) {
      h[c][j] = ts * acc[j];
      pa += dot4(h[c][j], h[c][j]);
    }
    grp_reduce<1>(&pa);
    {
      float n1  = fsqrt_(pa);
      float n1m = fmaxf(n1, 1e-8f);
      float c1  = fminf(n1m, 1.5f) * frcp(n1m);   // clip-to-1.5 scale
      float n2  = c1 * n1;                        // norm after clip
      float nsx = fmaxf(n2, 1e-9f);
      float sh  = fsinh(n2);
      float rn  = frcp(nsx);
      float g   = sh * c1 * rn;
      float sxr = sh * n2 * rn;                   // ||xr||
      float xx0 = fsqrt_(fmaf(sxr, sxr, 1.f));    // projx
#pragma unroll
      for (int j = 0; j < 4; ++j) h[c][j] = g * h[c][j];
      x0s[c] = xx0;
      r2s[c] = g * g * pa;                        // ||xr||^2, algebraic
      float* o = out + (size_t)c * HOFF + (size_t)pt * OUTS;
      if (m == 0) o[0] = xx0;
#pragma unroll
      for (int j = 0; j < 4; ++j) {
        int base = 1 + 4 * m + 64 * j;
        f4 v = h[c][j];
        o[base] = v.x; o[base + 1] = v.y; o[base + 2] = v.z; o[base + 3] = v.w;
      }
    }
  }

  // ---- lorentz fusion (each 16-lane group owns one point) ----
  float wt0 = 0.f;
  f4    wtr[4];
#pragma unroll
  for (int j = 0; j < 4; ++j) wtr[j] = (f4){0.f, 0.f, 0.f, 0.f};
#pragma unroll
  for (int c = 0; c < 4; ++c) {
    float y0    = x0s[c];
    float alpha = fmaxf(y0, 1.f + 1e-7f);
    float dist  = facosh(alpha);
    float u0    = y0 - alpha;
    float msq   = r2s[c] - u0 * u0;
    float un    = fsqrt_(fmaxf(msq, 1e-12f));
    float f     = wgt[c] * dist * frcp(un);
    wt0 = fmaf(f, u0, wt0);
#pragma unroll
    for (int j = 0; j < 4; ++j) wtr[j] = fma4s(f, h[c][j], wtr[j]);
  }
  float rrp = 0.f;
#pragma unroll
  for (int j = 0; j < 4; ++j) rrp += dot4(wtr[j], wtr[j]);
  grp_reduce<1>(&rrp);

  f4    mr[4];
  float mrr, m0;
  {
    float rr  = rrp;
    float nrm = fsqrt_(fmaf(wt0, wt0, rr));
    float scl = fminf(nrm, 2.f) * frcp(fmaxf(nrm, 1e-12f));
    float nr  = scl * fsqrt_(rr);                 // spatial norm after clip
    float nsx = fmaxf(nr, 1e-9f);
    float g   = fsinh(nr) * scl * frcp(nsx);
#pragma unroll
    for (int j = 0; j < 4; ++j) mr[j] = g * wtr[j];
    mrr = g * g * rr;                             // ||mr||^2, algebraic
    m0  = fsqrt_(1.f + mrr);                      // projx
  }

#pragma unroll 1
  for (int it = 0; it < 5; ++it) {
    float dots[4];
#pragma unroll
    for (int c = 0; c < 4; ++c) {
      float d = 0.f;
#pragma unroll
      for (int j = 0; j < 4; ++j) d += dot4(mr[j], h[c][j]);
      dots[c] = d;
    }
    grp_reduce<4>(dots);

    float wv0 = 0.f;
    f4    wvr[4];
#pragma unroll
    for (int j = 0; j < 4; ++j) wvr[j] = (f4){0.f, 0.f, 0.f, 0.f};
#pragma unroll
    for (int c = 0; c < 4; ++c) {
      float d     = dots[c];
      float y0    = x0s[c];
      float ip    = fmaf(m0, y0, -d);             // -mink(mean, y)
      float alpha = fmaxf(ip, 1.f + 1e-7f);
      float dist  = facosh(alpha);
      float u0    = fmaf(-alpha, m0, y0);
      // ||ur||^2 = r2 - 2*alpha*dot + alpha^2*mrr (algebraic)
      float t   = fmaf(alpha, mrr, -2.f * d);
      float s2  = fmaf(alpha, t, r2s[c]);
      float msq = s2 - u0 * u0;
      float un  = fsqrt_(fmaxf(msq, 1e-12f));
      float f   = wgt[c] * dist * frcp(un);
      wv0 = fmaf(f, u0, wv0);
#pragma unroll
      for (int j = 0; j < 4; ++j) {
        f4 diff = fma4s(-alpha, mr[j], h[c][j]);
        wvr[j]  = fma4s(f, diff, wvr[j]);
      }
    }
    float pr[2] = {0.f, 0.f};
#pragma unroll
    for (int j = 0; j < 4; ++j) {
      pr[0] += dot4(wvr[j], wvr[j]);
      pr[1] += dot4(mr[j], wvr[j]);
    }
    grp_reduce<2>(pr);

    {
      float rr2  = pr[0];
      float mwv  = pr[1];
      float nrm2 = fsqrt_(fmaf(wv0, wv0, rr2));
      float sc2  = fminf(nrm2, 2.f) * frcp(fmaxf(nrm2, 1e-12f));
      float tt   = 0.1f * sc2;                    // fold clip + 0.1 step
      float msqu = tt * tt * (rr2 - wv0 * wv0);   // mink(u,u)
      float un2  = fsqrt_(fmaxf(msqu, 1e-12f));
      float shv, chv;
      fsinhcosh(un2, shv, chv);
      float gg = shv * tt * frcp(un2);
#pragma unroll
      for (int j = 0; j < 4; ++j) mr[j] = fma4s(chv, mr[j], gg * wvr[j]);
      // ||mr'||^2 = chv^2*mrr + 2*chv*gg*(mr.wvr) + gg^2*rr2 (algebraic)
      mrr = chv * chv * mrr + 2.f * chv * gg * mwv + gg * gg * rr2;
      m0  = fsqrt_(1.f + mrr);                    // projx
    }
  }

  {
    float* o = out + 4 * HOFF + (size_t)pt * OUTS;
    if (m == 0) o[0] = m0;
#pragma unroll
    for (int j = 0; j < 4; ++j) {
      int base = 1 + 4 * m + 64 * j;
      f4 v = mr[j];
      o[base] = v.x; o[base + 1] = v.y; o[base + 2] = v.z; o[base + 3] = v.w;
    }
  }
}

}  // namespace

extern "C" void kernel_launch(void* const* d_in, const int* in_sizes, int n_in,
                              void* d_out, int out_size, void* d_ws, size_t ws_size,
                              hipStream_t stream) {
  (void)in_sizes; (void)n_in; (void)out_size; (void)d_ws; (void)ws_size;
  splmw_kernel<<<GRID, 256, 0, stream>>>(
      (const float*)d_in[0], (const float*)d_in[1], (const float*)d_in[2],
      (const float*)d_in[3], (const float*)d_in[4], (const float*)d_in[5],
      (const float*)d_in[6], (const float*)d_in[7], (const float*)d_in[8],
      (const float*)d_in[9], (const float*)d_in[10], (const float*)d_in[11],
      (const float*)d_in[12], (const float*)d_in[13], (float*)d_out);
}

// Round 3
// 268.820 us; speedup vs baseline: 1.0465x; 1.0465x over previous
//
#include <hip/hip_runtime.h>
#include <math.h>

namespace {

typedef float f4 __attribute__((ext_vector_type(4)));

constexpr int PPW  = 4;                    // points per wave
constexpr int WPB  = 4;                    // waves per block
constexpr int PPB  = PPW * WPB;            // 16 points per block
constexpr int NPTS = 256 * 128;            // 32768 points total
constexpr int GRID = NPTS / PPB;           // 2048 blocks
constexpr int OUTS = 257;                  // D+1
constexpr size_t HOFF = (size_t)NPTS * OUTS;
constexpr int WSTR = 256;                  // wlds row stride (balanced banks)
constexpr int HSTR = 260;                  // hlds row stride; 260%32==4 -> group rows
                                           // land on distinct bank-quads (balanced)

__device__ __forceinline__ float frcp(float x)   { return __builtin_amdgcn_rcpf(x); }
__device__ __forceinline__ float fsqrt_(float x) { return __builtin_amdgcn_sqrtf(x); }
// acosh(a) = log(a + sqrt(a^2-1)); fma keeps a^2-1 accurate near a=1
__device__ __forceinline__ float facosh(float a) {
  return __logf(a + fsqrt_(fmaf(a, a, -1.f)));
}
__device__ __forceinline__ void fsinhcosh(float x, float& sh, float& ch) {
  float e = __expf(x), ei = frcp(e);
  sh = 0.5f * (e - ei);
  ch = 0.5f * (e + ei);
}
__device__ __forceinline__ float fsinh(float x) {
  float e = __expf(x);
  return 0.5f * (e - frcp(e));
}
__device__ __forceinline__ float dot4(f4 a, f4 b) {
  return a.x * b.x + a.y * b.y + a.z * b.z + a.w * b.w;
}
__device__ __forceinline__ f4 fma4s(float a, f4 b, f4 c) {
  f4 av = {a, a, a, a};
  return __builtin_elementwise_fma(av, b, c);
}

// one butterfly step: x += rotate-within-row16(x, N) — pure VALU (v_add_f32+DPP)
template <int CTRL>
__device__ __forceinline__ float dpp_add(float x) {
  int t = __builtin_amdgcn_update_dpp(0, __builtin_bit_cast(int, x), CTRL, 0xf, 0xf, true);
  return x + __builtin_bit_cast(float, t);
}

// sum across each 16-lane row via DPP rotations (8,4,2,1)
template <int NB>
__device__ __forceinline__ void grp_reduce(float* v) {
#pragma unroll
  for (int i = 0; i < NB; ++i) {
    float t = v[i];
    t = dpp_add<0x128>(t);   // row_ror:8
    t = dpp_add<0x124>(t);   // row_ror:4
    t = dpp_add<0x122>(t);   // row_ror:2
    t = dpp_add<0x121>(t);   // row_ror:1
    v[i] = t;
  }
}

__global__ __launch_bounds__(256) void splmw_kernel(
    const float* __restrict__ xt, const float* __restrict__ xc,
    const float* __restrict__ xf, const float* __restrict__ xr,
    const float* __restrict__ Wt, const float* __restrict__ bt,
    const float* __restrict__ Wc, const float* __restrict__ bc,
    const float* __restrict__ Wf, const float* __restrict__ bf,
    const float* __restrict__ Wr, const float* __restrict__ br,
    const float* __restrict__ esp, const float* __restrict__ lwp,
    float* __restrict__ out) {
  // W^T staged as wlds[s*WSTR + d] (write: lanes vary d -> contiguous, free;
  // read: 64 consecutive dwords -> balanced). hlds: per-wave transpose scratch.
  __shared__ float wlds[32 * WSTR];              // 32 KiB
  __shared__ float hlds[WPB * PPW * HSTR];       // 16.6 KiB

  const int tid  = threadIdx.x;
  const int lane = tid & 63;
  const int m    = lane & 15;              // lane within 16-lane group
  const int grp  = lane >> 4;              // group (= point) within wave
  const int wv   = __builtin_amdgcn_readfirstlane(tid >> 6);
  const int pt0  = blockIdx.x * PPB + wv * PPW;  // wave's first point (uniform)
  const int pt   = pt0 + grp;                    // this lane's point
  float* hw = hlds + wv * (PPW * HSTR);          // this wave's scratch

  // tanh(effective_scale) via native exp
  float es2 = __expf(2.f * esp[0]);
  const float ts = (es2 - 1.f) * frcp(es2 + 1.f);
  // softmax of lorentz_weights
  float l0 = lwp[0], l1 = lwp[1], l2 = lwp[2], l3 = lwp[3];
  float mx = fmaxf(fmaxf(l0, l1), fmaxf(l2, l3));
  float e0 = __expf(l0 - mx), e1 = __expf(l1 - mx);
  float e2 = __expf(l2 - mx), e3 = __expf(l3 - mx);
  float ei = frcp(e0 + e1 + e2 + e3);
  const float wgt[4] = {e0 * ei, e1 * ei, e2 * ei, e3 * ei};

  const float* xsarr[4] = {xt, xc, xf, xr};
  const float* Wsarr[4] = {Wt, Wc, Wf, Wr};
  const float* Bsarr[4] = {bt, bc, bf, br};

  // h[c][j]: this lane's point's spatial dims 4m+64j .. +3 (group layout)
  f4    h[4][4];
  float x0s[4];
  float r2s[4];

#pragma unroll
  for (int c = 0; c < 4; ++c) {
    // ---- stage W_c transposed into LDS (thread tid owns W row d = tid) ----
    const float* Wp = Wsarr[c];
    f4 wrow[8];
#pragma unroll
    for (int k = 0; k < 8; ++k) wrow[k] = *(const f4*)(Wp + tid * 32 + 4 * k);
    __syncthreads();                       // prev channel's reads done
#pragma unroll
    for (int k = 0; k < 8; ++k) {
      wlds[(4 * k + 0) * WSTR + tid] = wrow[k].x;
      wlds[(4 * k + 1) * WSTR + tid] = wrow[k].y;
      wlds[(4 * k + 2) * WSTR + tid] = wrow[k].z;
      wlds[(4 * k + 3) * WSTR + tid] = wrow[k].w;
    }
    __syncthreads();

    // ---- encode, 64-lane layout: lane owns dims 4*lane..4*lane+3 of ALL
    // 4 points; each W fragment read feeds 4 FMAs (4x fewer LDS reads) ----
    f4 acc[PPW];
    {
      f4 bv = ((const f4*)Bsarr[c])[lane];
#pragma unroll
      for (int p = 0; p < PPW; ++p) acc[p] = bv;
    }
    const float* xp = xsarr[c] + (size_t)pt0 * 32;   // wave-uniform -> s_load
#pragma unroll
    for (int s4 = 0; s4 < 8; ++s4) {
      f4 q0 = *(const f4*)(xp + 4 * s4);
      f4 q1 = *(const f4*)(xp + 32 + 4 * s4);
      f4 q2 = *(const f4*)(xp + 64 + 4 * s4);
      f4 q3 = *(const f4*)(xp + 96 + 4 * s4);
      float qa[4][4] = {{q0.x, q0.y, q0.z, q0.w}, {q1.x, q1.y, q1.z, q1.w},
                        {q2.x, q2.y, q2.z, q2.w}, {q3.x, q3.y, q3.z, q3.w}};
#pragma unroll
      for (int si = 0; si < 4; ++si) {
        f4 w4 = *(const f4*)&wlds[(4 * s4 + si) * WSTR + 4 * lane];
#pragma unroll
        for (int p = 0; p < PPW; ++p) acc[p] = fma4s(qa[p][si], w4, acc[p]);
      }
    }

    // ---- intra-wave transpose to group layout (private region, no barrier;
    // LDS pipe is in-order per wave) ----
#pragma unroll
    for (int p = 0; p < PPW; ++p) *(f4*)&hw[p * HSTR + 4 * lane] = acc[p];
    __builtin_amdgcn_wave_barrier();       // compiler ordering fence (no-op)
    f4 zj[4];
#pragma unroll
    for (int j = 0; j < 4; ++j) zj[j] = *(const f4*)&hw[grp * HSTR + 4 * m + 64 * j];

    // ---- to_hyperbolic (group layout; scalars once per lane) ----
    float pa = 0.f;
#pragma unroll
    for (int j = 0; j < 4; ++j) {
      h[c][j] = ts * zj[j];
      pa += dot4(h[c][j], h[c][j]);
    }
    grp_reduce<1>(&pa);
    {
      float n1  = fsqrt_(pa);
      float n1m = fmaxf(n1, 1e-8f);
      float c1  = fminf(n1m, 1.5f) * frcp(n1m);   // clip-to-1.5 scale
      float n2  = c1 * n1;                        // norm after clip
      float nsx = fmaxf(n2, 1e-9f);
      float sh  = fsinh(n2);
      float rn  = frcp(nsx);
      float g   = sh * c1 * rn;
      float sxr = sh * n2 * rn;                   // ||xr||
      float xx0 = fsqrt_(fmaf(sxr, sxr, 1.f));    // projx
#pragma unroll
      for (int j = 0; j < 4; ++j) h[c][j] = g * h[c][j];
      x0s[c] = xx0;
      r2s[c] = g * g * pa;                        // ||xr||^2, algebraic
      float* o = out + (size_t)c * HOFF + (size_t)pt * OUTS;
      if (m == 0) o[0] = xx0;
#pragma unroll
      for (int j = 0; j < 4; ++j) {
        int base = 1 + 4 * m + 64 * j;
        f4 v = h[c][j];
        o[base] = v.x; o[base + 1] = v.y; o[base + 2] = v.z; o[base + 3] = v.w;
      }
    }
  }

  // ---- lorentz fusion (each 16-lane group owns one point) ----
  float wt0 = 0.f;
  f4    wtr[4];
#pragma unroll
  for (int j = 0; j < 4; ++j) wtr[j] = (f4){0.f, 0.f, 0.f, 0.f};
#pragma unroll
  for (int c = 0; c < 4; ++c) {
    float y0    = x0s[c];
    float alpha = fmaxf(y0, 1.f + 1e-7f);
    float dist  = facosh(alpha);
    float u0    = y0 - alpha;
    float msq   = r2s[c] - u0 * u0;
    float un    = fsqrt_(fmaxf(msq, 1e-12f));
    float f     = wgt[c] * dist * frcp(un);
    wt0 = fmaf(f, u0, wt0);
#pragma unroll
    for (int j = 0; j < 4; ++j) wtr[j] = fma4s(f, h[c][j], wtr[j]);
  }
  float rrp = 0.f;
#pragma unroll
  for (int j = 0; j < 4; ++j) rrp += dot4(wtr[j], wtr[j]);
  grp_reduce<1>(&rrp);

  f4    mr[4];
  float mrr, m0;
  {
    float rr  = rrp;
    float nrm = fsqrt_(fmaf(wt0, wt0, rr));
    float scl = fminf(nrm, 2.f) * frcp(fmaxf(nrm, 1e-12f));
    float nr  = scl * fsqrt_(rr);                 // spatial norm after clip
    float nsx = fmaxf(nr, 1e-9f);
    float g   = fsinh(nr) * scl * frcp(nsx);
#pragma unroll
    for (int j = 0; j < 4; ++j) mr[j] = g * wtr[j];
    mrr = g * g * rr;                             // ||mr||^2, algebraic
    m0  = fsqrt_(1.f + mrr);                      // projx
  }

#pragma unroll 1
  for (int it = 0; it < 5; ++it) {
    float dots[4];
#pragma unroll
    for (int c = 0; c < 4; ++c) {
      float d = 0.f;
#pragma unroll
      for (int j = 0; j < 4; ++j) d += dot4(mr[j], h[c][j]);
      dots[c] = d;
    }
    grp_reduce<4>(dots);

    float wv0 = 0.f;
    f4    wvr[4];
#pragma unroll
    for (int j = 0; j < 4; ++j) wvr[j] = (f4){0.f, 0.f, 0.f, 0.f};
#pragma unroll
    for (int c = 0; c < 4; ++c) {
      float d     = dots[c];
      float y0    = x0s[c];
      float ip    = fmaf(m0, y0, -d);             // -mink(mean, y)
      float alpha = fmaxf(ip, 1.f + 1e-7f);
      float dist  = facosh(alpha);
      float u0    = fmaf(-alpha, m0, y0);
      // ||ur||^2 = r2 - 2*alpha*dot + alpha^2*mrr (algebraic)
      float t   = fmaf(alpha, mrr, -2.f * d);
      float s2  = fmaf(alpha, t, r2s[c]);
      float msq = s2 - u0 * u0;
      float un  = fsqrt_(fmaxf(msq, 1e-12f));
      float f   = wgt[c] * dist * frcp(un);
      wv0 = fmaf(f, u0, wv0);
#pragma unroll
      for (int j = 0; j < 4; ++j) {
        f4 diff = fma4s(-alpha, mr[j], h[c][j]);
        wvr[j]  = fma4s(f, diff, wvr[j]);
      }
    }
    float pr[2] = {0.f, 0.f};
#pragma unroll
    for (int j = 0; j < 4; ++j) {
      pr[0] += dot4(wvr[j], wvr[j]);
      pr[1] += dot4(mr[j], wvr[j]);
    }
    grp_reduce<2>(pr);

    {
      float rr2  = pr[0];
      float mwv  = pr[1];
      float nrm2 = fsqrt_(fmaf(wv0, wv0, rr2));
      float sc2  = fminf(nrm2, 2.f) * frcp(fmaxf(nrm2, 1e-12f));
      float tt   = 0.1f * sc2;                    // fold clip + 0.1 step
      float msqu = tt * tt * (rr2 - wv0 * wv0);   // mink(u,u)
      float un2  = fsqrt_(fmaxf(msqu, 1e-12f));
      float shv, chv;
      fsinhcosh(un2, shv, chv);
      float gg = shv * tt * frcp(un2);
#pragma unroll
      for (int j = 0; j < 4; ++j) mr[j] = fma4s(chv, mr[j], gg * wvr[j]);
      // ||mr'||^2 = chv^2*mrr + 2*chv*gg*(mr.wvr) + gg^2*rr2 (algebraic)
      mrr = chv * chv * mrr + 2.f * chv * gg * mwv + gg * gg * rr2;
      m0  = fsqrt_(1.f + mrr);                    // projx
    }
  }

  {
    float* o = out + 4 * HOFF + (size_t)pt * OUTS;
    if (m == 0) o[0] = m0;
#pragma unroll
    for (int j = 0; j < 4; ++j) {
      int base = 1 + 4 * m + 64 * j;
      f4 v = mr[j];
      o[base] = v.x; o[base + 1] = v.y; o[base + 2] = v.z; o[base + 3] = v.w;
    }
  }
}

}  // namespace

extern "C" void kernel_launch(void* const* d_in, const int* in_sizes, int n_in,
                              void* d_out, int out_size, void* d_ws, size_t ws_size,
                              hipStream_t stream) {
  (void)in_sizes; (void)n_in; (void)out_size; (void)d_ws; (void)ws_size;
  splmw_kernel<<<GRID, 256, 0, stream>>>(
      (const float*)d_in[0], (const float*)d_in[1], (const float*)d_in[2],
      (const float*)d_in[3], (const float*)d_in[4], (const float*)d_in[5],
      (const float*)d_in[6], (const float*)d_in[7], (const float*)d_in[8],
      (const float*)d_in[9], (const float*)d_in[10], (const float*)d_in[11],
      (const float*)d_in[12], (const float*)d_in[13], (float*)d_out);
}